// Round 8
// baseline (69.036 us; speedup 1.0000x reference)
//
#include <hip/hip_runtime.h>

typedef __attribute__((ext_vector_type(8))) short bf16x8;
typedef __attribute__((ext_vector_type(4))) float f32x4;

#define WT2_BYTES (8ull * 8 * 9 * 8192)           // 4,718,592

#define AS1C(p) ((const __attribute__((address_space(1))) void*)(p))
#define AS3(p)  ((__attribute__((address_space(3))) void*)(p))

static __device__ __forceinline__ ushort f2bf(float f) {
    union { float f; unsigned u; } v; v.f = f;
    unsigned r = v.u + 0x7FFF + ((v.u >> 16) & 1);   // RNE
    return (ushort)(r >> 16);
}
static __device__ __forceinline__ unsigned cvtpk(float a, float b) {
    unsigned r;
    asm("v_cvt_pk_bf16_f32 %0, %1, %2" : "=v"(r) : "v"(a), "v"(b));
    return r;   // lo = bf16(a), hi = bf16(b)
}

// w: (8 dk, 64 o, 64 i, 8 c, 9 f) fp32
// -> wt2: (8 dk, 8 c, 9 f) slices of 8192 B; element (o,i) at byte
//    o*128 + ((i>>3) ^ (o&7))*16 + (i&7)*2   (XOR-swizzle baked in)
__global__ __launch_bounds__(256) void wprep3_kernel(const float* __restrict__ w,
                                                     ushort* __restrict__ wt) {
    __shared__ float raw[4608];          // [i][c*9+f]
    __shared__ ushort row[72 * 64];      // [c*9+f][swizzled 64 i]
    int bid = blockIdx.x;                // dk*64 + o
    int dk = bid >> 6, o = bid & 63;
    const float* src = w + (size_t)bid * 4608;
    int t = threadIdx.x;
    #pragma unroll
    for (int j = 0; j < 18; ++j) raw[t + 256 * j] = src[t + 256 * j];
    __syncthreads();
    int osw = o & 7;
    #pragma unroll
    for (int p = 0; p < 18; ++p) {
        int idx = t + 256 * p;           // (cf, i)
        int cf = idx >> 6, i = idx & 63;
        int c = cf / 9, f = cf - c * 9;
        row[cf * 64 + ((i >> 3) ^ osw) * 8 + (i & 7)] = f2bf(raw[i * 72 + c * 9 + f]);
    }
    __syncthreads();
    char* wb = (char*)wt + (size_t)dk * 8 * 9 * 8192 + o * 128;
    #pragma unroll
    for (int q = 0; q < 3; ++q) {
        int idx = q * 256 + t;           // (cf, cc)
        if (idx < 576) {
            int cf = idx >> 3, cc = idx & 7;
            *(uint4*)(wb + (size_t)cf * 8192 + cc * 16) = *(const uint4*)&row[cf * 64 + cc * 8];
        }
    }
}

// conv7: 64l x 64o block tile, 4 waves (2l x 2o, 32x32 each), acc=16 AGPR.
// LDS 25.6 KB -> 6 blocks/CU (24 waves/CU). Same proven structure as conv6:
// W per-tap LDS DMA double-buffer, fused X transpose, XOR swizzle everywhere.
__global__ __launch_bounds__(256, 6) void conv7_kernel(
    const float* __restrict__ x, const ushort* __restrict__ wt,
    const float* __restrict__ bias, float* __restrict__ out)
{
    __shared__ __align__(16) ushort XL[72 * 64];    //  9216 B, [r][i] swizzled
    __shared__ __align__(16) ushort WL[2 * 4096];   // 16384 B, 2 tap slices

    int bid = blockIdx.x;
    int b = bid / 520, rem = bid - b * 520;   // stride 520 ≡ 0 mod 8: b-sharers same XCD
    int dk = rem / 65, tile = rem - dk * 65;
    int c, j;
    if (tile < 56) { c = tile >> 3; j = tile & 7; } else { c = 7; j = tile - 56; }
    int Sc = 505 * c, lb = j << 6;
    int V = ((c == 7) ? 561 : 505) - lb; if (V > 64) V = 64;
    int bdk = b * 8 + dk;
    int R0 = Sc + lb;                             // padded row of local row 0

    int t = threadIdx.x, lane = t & 63, wv = t >> 6;
    int ln16 = lane & 15, g = lane >> 4;
    int wr = wv >> 1, wc = wv & 1;                // wave tile: l-half / o-half
    int Lw = wr << 5, Ow = wc << 5;               // 32l x 32o per wave

    // ---- issue W tap 0 DMA first (latency overlap with X stage) ----
    const char* wsl = (const char*)wt + (size_t)(dk * 8 + c) * 9 * 8192;
    auto stageW = [&](int f, int buf) {
        __builtin_amdgcn_global_load_lds(AS1C(wsl + (size_t)f * 8192 + t * 16),
                                         AS3((char*)WL + buf * 8192 + t * 16), 16, 0, 0);
        __builtin_amdgcn_global_load_lds(AS1C(wsl + (size_t)f * 8192 + 4096 + t * 16),
                                         AS3((char*)WL + buf * 8192 + 4096 + t * 16), 16, 0, 0);
    };
    stageW(0, 0);

    // ---- stage X: fp32 -> bf16 transpose into swizzled LDS (72 rows) ----
    {
        const float* xb = x + ((size_t)(bdk * 64 + wv * 16)) * 4096;  // wave's 16 i-rows
        bool edge = (R0 < 4) || (R0 > 4028);
        #pragma unroll
        for (int k = 0; k < 2; ++k) {
            int r = k * 64 + lane;                // local row (l-position)
            if (r < 72) {
                int xr = R0 + r - 4;              // x row index
                float v[16];
                if (!edge) {
                    #pragma unroll
                    for (int q = 0; q < 16; ++q) v[q] = xb[(size_t)q * 4096 + xr];
                } else {
                    bool ok = (xr >= 0) && (xr < 4096);
                    int xc = ok ? xr : 0;
                    #pragma unroll
                    for (int q = 0; q < 16; ++q) v[q] = ok ? xb[(size_t)q * 4096 + xc] : 0.0f;
                }
                uint4 A, B;
                A.x = cvtpk(v[0], v[1]);   A.y = cvtpk(v[2], v[3]);
                A.z = cvtpk(v[4], v[5]);   A.w = cvtpk(v[6], v[7]);
                B.x = cvtpk(v[8], v[9]);   B.y = cvtpk(v[10], v[11]);
                B.z = cvtpk(v[12], v[13]); B.w = cvtpk(v[14], v[15]);
                char* base = (char*)XL + r * 128;
                *(uint4*)(base + (((2 * wv)     ^ (r & 7)) * 16)) = A;
                *(uint4*)(base + (((2 * wv + 1) ^ (r & 7)) * 16)) = B;
            }
        }
    }
    __syncthreads();    // X visible + W tap 0 resident (barrier drains vmcnt)

    f32x4 acc[2][2];
    #pragma unroll
    for (int a0 = 0; a0 < 2; ++a0)
        #pragma unroll
        for (int a1 = 0; a1 < 2; ++a1) acc[a0][a1] = (f32x4){0.f, 0.f, 0.f, 0.f};

    #pragma unroll 1
    for (int f = 0; f < 9; ++f) {
        int buf = f & 1;
        if (f < 8) stageW(f + 1, buf ^ 1);        // prefetch next tap
        int rbase = Lw + ln16 + f;
        int swz = rbase & 7;                      // +mf*16 doesn't change &7
        #pragma unroll
        for (int s = 0; s < 2; ++s) {
            int cof = ((s * 4 + g) ^ swz) * 16;
            int wof = buf * 8192 + ((s * 4 + g) ^ (ln16 & 7)) * 16;
            bf16x8 av[2], bv[2];
            #pragma unroll
            for (int mf = 0; mf < 2; ++mf)
                av[mf] = *(const bf16x8*)((const char*)XL + (rbase + mf * 16) * 128 + cof);
            #pragma unroll
            for (int nf = 0; nf < 2; ++nf)
                bv[nf] = *(const bf16x8*)((const char*)WL + wof + (Ow + nf * 16 + ln16) * 128);
            #pragma unroll
            for (int mf = 0; mf < 2; ++mf)
                #pragma unroll
                for (int nf = 0; nf < 2; ++nf)
                    acc[mf][nf] = __builtin_amdgcn_mfma_f32_16x16x32_bf16(av[mf], bv[nf], acc[mf][nf], 0, 0, 0);
        }
        if (f < 8) __syncthreads();   // waves done with buf; drains next-tap DMA
    }

    // ---- epilogue: bias + direct f32x4 stores (4 lanes = 64 B contiguous) ----
    float* ob = out + ((size_t)(bdk * 64)) * 4096 + Sc + lb;
    #pragma unroll
    for (int nf = 0; nf < 2; ++nf) {
        int o = Ow + nf * 16 + ln16;
        float bvs = bias[(dk * 64 + o) * 8 + c];
        #pragma unroll
        for (int mf = 0; mf < 2; ++mf) {
            int l = Lw + mf * 16 + g * 4;
            f32x4 vv = acc[mf][nf];
            vv[0] += bvs; vv[1] += bvs; vv[2] += bvs; vv[3] += bvs;
            if (l + 4 <= V) {
                *(f32x4*)(ob + (size_t)o * 4096 + l) = vv;
            } else if (l < V) {
                #pragma unroll
                for (int r = 0; r < 4; ++r)
                    if (l + r < V) ob[(size_t)o * 4096 + l + r] = vv[r];
            }
        }
    }
}

extern "C" void kernel_launch(void* const* d_in, const int* in_sizes, int n_in,
                              void* d_out, int out_size, void* d_ws, size_t ws_size,
                              hipStream_t stream) {
    const float* x    = (const float*)d_in[0];
    const float* wgt  = (const float*)d_in[1];
    const float* bias = (const float*)d_in[2];
    float* out        = (float*)d_out;
    ushort* wt2       = (ushort*)d_ws;            // 4,718,592 B

    hipLaunchKernelGGL(wprep3_kernel, dim3(512), dim3(256), 0, stream, wgt, wt2);
    hipLaunchKernelGGL(conv7_kernel, dim3(4160), dim3(256), 0, stream, x, wt2, bias, out);
}

// Round 9
// 54.252 us; speedup vs baseline: 1.2725x; 1.2725x over previous
//
#include <hip/hip_runtime.h>

typedef __attribute__((ext_vector_type(8))) short bf16x8;
typedef __attribute__((ext_vector_type(4))) float f32x4;

#define WT2_BYTES (8ull * 8 * 9 * 8192)           // 4,718,592

#define AS1C(p) ((const __attribute__((address_space(1))) void*)(p))
#define AS3(p)  ((__attribute__((address_space(3))) void*)(p))

static __device__ __forceinline__ ushort f2bf(float f) {
    union { float f; unsigned u; } v; v.f = f;
    unsigned r = v.u + 0x7FFF + ((v.u >> 16) & 1);   // RNE
    return (ushort)(r >> 16);
}
static __device__ __forceinline__ unsigned cvtpk(float a, float b) {
    unsigned r;
    asm("v_cvt_pk_bf16_f32 %0, %1, %2" : "=v"(r) : "v"(a), "v"(b));
    return r;   // lo = bf16(a), hi = bf16(b)
}

// w: (8 dk, 64 o, 64 i, 8 c, 9 f) fp32
// -> wt2: (8 dk, 8 c, 9 f) slices of 8192 B; element (o,i) at byte
//    o*128 + ((i>>3) ^ (o&7))*16 + (i&7)*2   (XOR-swizzle baked in)
__global__ __launch_bounds__(256) void wprep3_kernel(const float* __restrict__ w,
                                                     ushort* __restrict__ wt) {
    __shared__ float raw[4608];          // [i][c*9+f]
    __shared__ ushort row[72 * 64];      // [c*9+f][swizzled 64 i]
    int bid = blockIdx.x;                // dk*64 + o
    int dk = bid >> 6, o = bid & 63;
    const float* src = w + (size_t)bid * 4608;
    int t = threadIdx.x;
    #pragma unroll
    for (int j = 0; j < 18; ++j) raw[t + 256 * j] = src[t + 256 * j];
    __syncthreads();
    int osw = o & 7;
    #pragma unroll
    for (int p = 0; p < 18; ++p) {
        int idx = t + 256 * p;           // (cf, i)
        int cf = idx >> 6, i = idx & 63;
        int c = cf / 9, f = cf - c * 9;
        row[cf * 64 + ((i >> 3) ^ osw) * 8 + (i & 7)] = f2bf(raw[i * 72 + c * 9 + f]);
    }
    __syncthreads();
    char* wb = (char*)wt + (size_t)dk * 8 * 9 * 8192 + o * 128;
    #pragma unroll
    for (int q = 0; q < 3; ++q) {
        int idx = q * 256 + t;           // (cf, cc)
        if (idx < 576) {
            int cf = idx >> 3, cc = idx & 7;
            *(uint4*)(wb + (size_t)cf * 8192 + cc * 16) = *(const uint4*)&row[cf * 64 + cc * 8];
        }
    }
}

// conv8: 128l x 64o tile, 4 waves (2l x 2o, 64x32 each), acc=32.
// W: global_load_lds into 4-deep rolling LDS window, counted vmcnt (never 0
// until last tap), one barrier per tap. X: fused fp32->bf16 transpose, 136
// rows (fetch-granularity clean). LDS 50 KB -> 3 blocks/CU (12 waves/CU).
__global__ __launch_bounds__(256, 3) void conv8_kernel(
    const float* __restrict__ x, const ushort* __restrict__ wt,
    const float* __restrict__ bias, float* __restrict__ out)
{
    __shared__ __align__(16) ushort XL[136 * 64];   // 17408 B, [r][i] swizzled
    __shared__ __align__(16) ushort WL[4 * 4096];   // 32768 B, 4-tap window

    int bid = blockIdx.x;
    int bdk = bid / 33, tile = bid - bdk * 33;
    int dk = bdk & 7;
    int c, lt;
    if (tile < 28) { c = tile >> 2; lt = tile & 3; } else { c = 7; lt = tile - 28; }
    int Sc = 505 * c, lb = lt << 7;
    int V = ((c == 7) ? 561 : 505) - lb; if (V > 128) V = 128;
    int R0 = Sc + lb;                             // padded row of local row 0

    int t = threadIdx.x, lane = t & 63, wv = t >> 6;
    int ln16 = lane & 15, g = lane >> 4;
    int wr = wv >> 1, wc = wv & 1;                // wave tile: l-half / o-half
    int Lw = wr << 6, Ow = wc << 5;               // 64l x 32o per wave

    const char* wsl = (const char*)wt + (size_t)(dk * 8 + c) * 9 * 8192;
    auto stageW = [&](int f, int buf) {
        __builtin_amdgcn_global_load_lds(AS1C(wsl + (size_t)f * 8192 + t * 16),
                                         AS3((char*)WL + buf * 8192 + t * 16), 16, 0, 0);
        __builtin_amdgcn_global_load_lds(AS1C(wsl + (size_t)f * 8192 + 4096 + t * 16),
                                         AS3((char*)WL + buf * 8192 + 4096 + t * 16), 16, 0, 0);
    };
    // prologue: W0..W2 in flight before the X stage
    stageW(0, 0); stageW(1, 1); stageW(2, 2);

    // ---- stage X: fp32 -> bf16 transpose into swizzled LDS (136 rows) ----
    {
        const float* xb = x + ((size_t)(bdk * 64 + wv * 16)) * 4096;  // wave's 16 i-rows
        bool edge = (R0 < 4) || (R0 > 3964);
        #pragma unroll
        for (int k = 0; k < 3; ++k) {
            int r = k * 64 + lane;                // local row (l-position)
            if (r < 136) {
                int xr = R0 + r - 4;              // x row index
                float v[16];
                if (!edge) {
                    #pragma unroll
                    for (int q = 0; q < 16; ++q) v[q] = xb[(size_t)q * 4096 + xr];
                } else {
                    bool ok = (xr >= 0) && (xr < 4096);
                    int xc = ok ? xr : 0;
                    #pragma unroll
                    for (int q = 0; q < 16; ++q) v[q] = ok ? xb[(size_t)q * 4096 + xc] : 0.0f;
                }
                uint4 A, B;
                A.x = cvtpk(v[0], v[1]);   A.y = cvtpk(v[2], v[3]);
                A.z = cvtpk(v[4], v[5]);   A.w = cvtpk(v[6], v[7]);
                B.x = cvtpk(v[8], v[9]);   B.y = cvtpk(v[10], v[11]);
                B.z = cvtpk(v[12], v[13]); B.w = cvtpk(v[14], v[15]);
                char* base = (char*)XL + r * 128;
                *(uint4*)(base + (((2 * wv)     ^ (r & 7)) * 16)) = A;
                *(uint4*)(base + (((2 * wv + 1) ^ (r & 7)) * 16)) = B;
            }
        }
    }

    f32x4 acc[4][2];
    #pragma unroll
    for (int a0 = 0; a0 < 4; ++a0)
        #pragma unroll
        for (int a1 = 0; a1 < 2; ++a1) acc[a0][a1] = (f32x4){0.f, 0.f, 0.f, 0.f};

    auto tap = [&](int f) {
        int buf = f & 3;
        int rbase = Lw + ln16 + f;
        int swz = rbase & 7;                      // +mf*16 doesn't change &7
        #pragma unroll
        for (int s = 0; s < 2; ++s) {
            int cof = ((s * 4 + g) ^ swz) * 16;
            int wof = buf * 8192 + ((s * 4 + g) ^ (ln16 & 7)) * 16;
            bf16x8 av[4], bv[2];
            #pragma unroll
            for (int mf = 0; mf < 4; ++mf)
                av[mf] = *(const bf16x8*)((const char*)XL + (rbase + mf * 16) * 128 + cof);
            #pragma unroll
            for (int nf = 0; nf < 2; ++nf)
                bv[nf] = *(const bf16x8*)((const char*)WL + wof + (Ow + nf * 16 + ln16) * 128);
            #pragma unroll
            for (int mf = 0; mf < 4; ++mf)
                #pragma unroll
                for (int nf = 0; nf < 2; ++nf)
                    acc[mf][nf] = __builtin_amdgcn_mfma_f32_16x16x32_bf16(av[mf], bv[nf], acc[mf][nf], 0, 0, 0);
        }
    };

    // my X ds_writes done before the first barrier
    asm volatile("s_waitcnt lgkmcnt(0)" ::: "memory");

    // Per tap f: vmcnt(N) ensures W_f landed (at most W_{f+1},W_{f+2} = 4 ops
    // still in flight); barrier => all waves' tap f-1 done => buf (f-1)&3 free,
    // so issue W_{f+3} into it. Never drains the pipeline to 0 until tap 8.
#define TAPSTEP(N, F, ISSUE) \
    asm volatile("s_waitcnt vmcnt(" #N ")" ::: "memory"); \
    __builtin_amdgcn_s_barrier(); \
    __builtin_amdgcn_sched_barrier(0); \
    if (ISSUE) stageW(F + 3, (F + 3) & 3); \
    tap(F);

    TAPSTEP(4, 0, 1) TAPSTEP(4, 1, 1) TAPSTEP(4, 2, 1) TAPSTEP(4, 3, 1)
    TAPSTEP(4, 4, 1) TAPSTEP(4, 5, 1) TAPSTEP(4, 6, 0) TAPSTEP(2, 7, 0)
    TAPSTEP(0, 8, 0)
#undef TAPSTEP

    // ---- epilogue: bias + direct f32x4 stores (4 lanes = 64 B contiguous) ----
    float* ob = out + ((size_t)(bdk * 64)) * 4096 + Sc + lb;
    #pragma unroll
    for (int nf = 0; nf < 2; ++nf) {
        int o = Ow + nf * 16 + ln16;
        float bvs = bias[(dk * 64 + o) * 8 + c];
        #pragma unroll
        for (int mf = 0; mf < 4; ++mf) {
            int l = Lw + mf * 16 + g * 4;
            f32x4 vv = acc[mf][nf];
            vv[0] += bvs; vv[1] += bvs; vv[2] += bvs; vv[3] += bvs;
            if (l + 4 <= V) {
                *(f32x4*)(ob + (size_t)o * 4096 + l) = vv;
            } else if (l < V) {
                #pragma unroll
                for (int r = 0; r < 4; ++r)
                    if (l + r < V) ob[(size_t)o * 4096 + l + r] = vv[r];
            }
        }
    }
}

extern "C" void kernel_launch(void* const* d_in, const int* in_sizes, int n_in,
                              void* d_out, int out_size, void* d_ws, size_t ws_size,
                              hipStream_t stream) {
    const float* x    = (const float*)d_in[0];
    const float* wgt  = (const float*)d_in[1];
    const float* bias = (const float*)d_in[2];
    float* out        = (float*)d_out;
    ushort* wt2       = (ushort*)d_ws;            // 4,718,592 B

    hipLaunchKernelGGL(wprep3_kernel, dim3(512), dim3(256), 0, stream, wgt, wt2);
    hipLaunchKernelGGL(conv8_kernel, dim3(2112), dim3(256), 0, stream, x, wt2, bias, out);
}